// Round 6
// baseline (309.463 us; speedup 1.0000x reference)
//
#include <hip/hip_runtime.h>
#include <hip/hip_bf16.h>
#include <cstddef>
#include <cstdint>

#define B_ 2
#define D_ 12
#define H_ 200
#define W_ 200
#define HW_ (H_ * W_)
#define DHW_ (D_ * H_ * W_)
#define CELLS_ (B_ * D_ * H_ * W_)   // 960000
#define N_ 60000
#define CIN_ 2
#define COUT_ 64
#define K27 27
#define EPS_ 1e-5f
#define WSZ (K27 * CIN_ * COUT_)     // 3456 floats = 13.8 KB

typedef float vfloat4 __attribute__((ext_vector_type(4)));  // clang-native

// ---------------------------------------------------------------------------
// Kernel A: build dense cell -> (f0,f1) feature grid. scatter[13][n] is the
// identity tap = point n's own cell (always in-bounds). fgrid pre-set to NaN
// (memset 0xFF); occupied cells get the point's feature pair. The gather
// kernel tests occupancy via f.x==f.x, so NaN never enters arithmetic.
// ---------------------------------------------------------------------------
__global__ void fill_fgrid_kernel(const int* __restrict__ scatter,
                                  const float2* __restrict__ feat2,
                                  float2* __restrict__ fgrid) {
    int n = blockIdx.x * blockDim.x + threadIdx.x;
    if (n >= N_) return;
    fgrid[scatter[13 * N_ + n]] = feat2[n];
}

// ---------------------------------------------------------------------------
// Kernel B: fused stencil-gather conv + LayerNorm + ReLU.
// 16 lanes per cell, float4 (4 channels) per lane, 16 cells per 256-thr block.
//   probe: lane q loads fgrid at tap q (round 1) and tap q+16 (round 2);
//          feature VALUES land in registers, occupancy = !isnan
//   hit loop (avg 1.7/cell): ffs -> shfl-broadcast (f0,f1) from the probing
//          lane -> 2x ds_read_b128 weight (LDS, conflict-free) -> 8 FMA.
//          No global memory in the loop.
//   LN: width-16 butterfly; nontemporal float4 store (write-once stream,
//          don't evict fgrid from L2).
// ---------------------------------------------------------------------------
__global__ __launch_bounds__(256) void gather_fgrid_kernel(
        const float2* __restrict__ fgrid,
        const float* __restrict__ weight,
        const float* __restrict__ gamma,
        const float* __restrict__ beta,
        float* __restrict__ out) {
    __shared__ float w_lds[WSZ];
    {   // stage 27x2x64 weights: 864 float4 loads, coalesced
        float4* wv = reinterpret_cast<float4*>(w_lds);
        const float4* ws = reinterpret_cast<const float4*>(weight);
        for (int i = threadIdx.x; i < WSZ / 4; i += 256) wv[i] = ws[i];
    }
    __syncthreads();

    const int tid  = threadIdx.x;
    const int slot = tid >> 4;              // cell slot within block, 0..15
    const int q    = tid & 15;              // lane within 16-lane group
    const int gw   = slot & 3;              // group within wave, 0..3

    const int x  = blockIdx.x * 16 + slot;  // cell x
    const int y  = blockIdx.y;              // cell y
    const int bz = blockIdx.z;              // b*D + z  (0..23)
    const int z  = bz >= D_ ? bz - D_ : bz; // z within batch (uniform)
    const bool cell_ok = (x < W_);

    const int cbase = (bz * H_ + y) * W_ + x;   // this cell's linear index

    const float fnan = __int_as_float(-1);      // NaN sentinel
    float2 f1 = {fnan, fnan}, f2 = {fnan, fnan};

    // ---- probe round 1: taps 0..15 ----
    {
        int fz = q / 9, t = q - fz * 9;
        int fy = t / 3, fx = t - fy * 3;
        int pz = z + fz - 1, py = y + fy - 1, px = x + fx - 1;
        if (cell_ok && (unsigned)pz < D_ && (unsigned)py < H_ && (unsigned)px < W_)
            f1 = fgrid[cbase + (fz - 1) * HW_ + (fy - 1) * W_ + (fx - 1)];
    }
    // ---- probe round 2: taps 16..26 (lanes 0..10) ----
    if (q < K27 - 16) {
        int tap = q + 16;
        int fz = tap / 9, t = tap - fz * 9;
        int fy = t / 3, fx = t - fy * 3;
        int pz = z + fz - 1, py = y + fy - 1, px = x + fx - 1;
        if (cell_ok && (unsigned)pz < D_ && (unsigned)py < H_ && (unsigned)px < W_)
            f2 = fgrid[cbase + (fz - 1) * HW_ + (fy - 1) * W_ + (fx - 1)];
    }

    unsigned long long ball1 = __ballot(f1.x == f1.x);
    unsigned long long ball2 = __ballot(f2.x == f2.x);
    const int shift = gw * 16;
    unsigned int mask = (unsigned int)((ball1 >> shift) & 0xFFFFull)
                      | ((unsigned int)((ball2 >> shift) & 0x7FFull) << 16);
    const bool active = (mask != 0u);

    // ---- gather-conv over actual hits: all in-register + LDS ----
    float4 acc = {0.f, 0.f, 0.f, 0.f};
    while (mask) {
        int l = __ffs(mask) - 1;            // tap index == weight k (ascending)
        mask &= mask - 1;
        int src = (gw << 4) + (l & 15);     // probing lane in this wave
        float fx0 = __shfl((l < 16) ? f1.x : f2.x, src, 64);
        float fy0 = __shfl((l < 16) ? f1.y : f2.y, src, 64);
        const float* wk = &w_lds[l * (CIN_ * COUT_) + q * 4];
        float4 w0 = *reinterpret_cast<const float4*>(wk);
        float4 w1 = *reinterpret_cast<const float4*>(wk + COUT_);
        acc.x += fx0 * w0.x + fy0 * w1.x;
        acc.y += fx0 * w0.y + fy0 * w1.y;
        acc.z += fx0 * w0.z + fy0 * w1.z;
        acc.w += fx0 * w0.w + fy0 * w1.w;
    }

    // ---- LayerNorm over 64 channels: butterfly across the 16-lane group ----
    float s  = acc.x + acc.y + acc.z + acc.w;
    float s2 = acc.x * acc.x + acc.y * acc.y + acc.z * acc.z + acc.w * acc.w;
    #pragma unroll
    for (int m = 1; m < 16; m <<= 1) {
        s  += __shfl_xor(s,  m, 16);
        s2 += __shfl_xor(s2, m, 16);
    }
    float mu  = s * (1.0f / COUT_);
    float var = s2 * (1.0f / COUT_) - mu * mu;
    float inv = rsqrtf(var + EPS_);

    float4 gm = *reinterpret_cast<const float4*>(&gamma[q * 4]);
    float4 bt = *reinterpret_cast<const float4*>(&beta[q * 4]);

    vfloat4 r;
    if (active) {
        r.x = fmaxf((acc.x - mu) * inv * gm.x + bt.x, 0.0f);
        r.y = fmaxf((acc.y - mu) * inv * gm.y + bt.y, 0.0f);
        r.z = fmaxf((acc.z - mu) * inv * gm.z + bt.z, 0.0f);
        r.w = fmaxf((acc.w - mu) * inv * gm.w + bt.w, 0.0f);
    } else {
        r.x = r.y = r.z = r.w = 0.0f;       // inactive -> exact zeros
    }

    if (cell_ok) {
        vfloat4* dst = reinterpret_cast<vfloat4*>(&out[(size_t)cbase * COUT_ + q * 4]);
        __builtin_nontemporal_store(r, dst);
    }
}

extern "C" void kernel_launch(void* const* d_in, const int* in_sizes, int n_in,
                              void* d_out, int out_size, void* d_ws, size_t ws_size,
                              hipStream_t stream) {
    const float* feat    = (const float*)d_in[0];   // (N, 2)
    const float* weight  = (const float*)d_in[1];   // (27, 2, 64)
    const float* gamma   = (const float*)d_in[2];   // (64,)
    const float* beta    = (const float*)d_in[3];   // (64,)
    const int*   scatter = (const int*)d_in[4];     // (27, N)
    float* out = (float*)d_out;                     // (CELLS, 64)

    float2* fgrid = (float2*)d_ws;                  // CELLS * 8 B = 7.68 MB

    // fgrid := NaN everywhere (0xFF bytes), then 60k feature-pair writes
    (void)hipMemsetAsync(fgrid, 0xFF, (size_t)CELLS_ * sizeof(float2), stream);
    {
        int block = 256;
        int grid = (N_ + block - 1) / block;
        fill_fgrid_kernel<<<grid, block, 0, stream>>>(scatter,
                                                      (const float2*)feat, fgrid);
    }

    // fused gather-conv + LN + ReLU: 16 cells per 256-thread block
    {
        dim3 block(256, 1, 1);
        dim3 grid((W_ + 15) / 16, H_, B_ * D_);     // 13 x 200 x 24
        gather_fgrid_kernel<<<grid, block, 0, stream>>>(fgrid, weight, gamma,
                                                        beta, out);
    }
}